// Round 1
// baseline (345.522 us; speedup 1.0000x reference)
//
#include <hip/hip_runtime.h>

typedef unsigned short u16;
typedef __bf16 bf16x8 __attribute__((ext_vector_type(8)));
typedef float f32x4 __attribute__((ext_vector_type(4)));

typedef __attribute__((address_space(1))) const void* as1cv;
typedef __attribute__((address_space(3))) void* as3v;

__device__ __forceinline__ u16 f2bf(float f) {
  union { float f; unsigned u; } v;
  v.f = f;
  unsigned r = (v.u + 0x7fffu + ((v.u >> 16) & 1u)) >> 16;
  return (u16)r;
}

__device__ __forceinline__ void gload16(const void* g, void* l) {
  __builtin_amdgcn_global_load_lds((as1cv)g, (as3v)l, 16, 0, 0);
}

// ---------------- LayerNorm: fp32 [rows][1024] -> bf16 ----------------
__global__ __launch_bounds__(256)
void ln_kernel(const float* __restrict__ x, const float* __restrict__ g,
               const float* __restrict__ be, u16* __restrict__ out) {
  __shared__ float red[8];
  const int row = blockIdx.x;
  const int tid = threadIdx.x;
  const float4 v = ((const float4*)(x + (size_t)row * 1024))[tid];
  float s = v.x + v.y + v.z + v.w;
#pragma unroll
  for (int off = 1; off < 64; off <<= 1) s += __shfl_xor(s, off, 64);
  const int wv = tid >> 6, lane = tid & 63;
  if (lane == 0) red[wv] = s;
  __syncthreads();
  s = red[0] + red[1] + red[2] + red[3];
  const float mu = s * (1.0f / 1024.0f);
  const float d0 = v.x - mu, d1 = v.y - mu, d2 = v.z - mu, d3 = v.w - mu;
  float q = d0 * d0 + d1 * d1 + d2 * d2 + d3 * d3;
#pragma unroll
  for (int off = 1; off < 64; off <<= 1) q += __shfl_xor(q, off, 64);
  if (lane == 0) red[4 + wv] = q;
  __syncthreads();
  q = red[4] + red[5] + red[6] + red[7];
  const float inv = rsqrtf(q * (1.0f / 1024.0f) + 1e-5f);
  const float4 gv = ((const float4*)g)[tid];
  const float4 bv = ((const float4*)be)[tid];
  unsigned p0 = (unsigned)f2bf(d0 * inv * gv.x + bv.x) |
                ((unsigned)f2bf(d1 * inv * gv.y + bv.y) << 16);
  unsigned p1 = (unsigned)f2bf(d2 * inv * gv.z + bv.z) |
                ((unsigned)f2bf(d3 * inv * gv.w + bv.w) << 16);
  uint2 o; o.x = p0; o.y = p1;
  *(uint2*)(out + (size_t)row * 1024 + tid * 4) = o;
}

// ---------- weight convert+transpose: fp32 [K][N] -> bf16 [N][K] ----------
__global__ __launch_bounds__(256)
void transpose_cvt(const float* __restrict__ in, u16* __restrict__ out,
                   int K, int N) {
  __shared__ float t[32][33];
  const int n0 = blockIdx.x * 32, k0 = blockIdx.y * 32;
  for (int r = threadIdx.y; r < 32; r += 8)
    t[r][threadIdx.x] = in[(size_t)(k0 + r) * N + n0 + threadIdx.x];
  __syncthreads();
  for (int r = threadIdx.y; r < 32; r += 8)
    out[(size_t)(n0 + r) * K + k0 + threadIdx.x] = f2bf(t[threadIdx.x][r]);
}

// ---------- V transpose: qkv bf16 [m][3072] (V slice) -> vT [bh][64][2048] ----------
__global__ __launch_bounds__(256)
void vtrans(const u16* __restrict__ qkv, u16* __restrict__ vT) {
  __shared__ u16 t[32][33];
  const int s0 = blockIdx.x * 32;
  const int bh = blockIdx.y;
  const int d0 = blockIdx.z * 32;
  const int b = bh >> 4, h = bh & 15;
  const u16* src = qkv + ((size_t)b * 2048) * 3072 + 2048 + h * 64;
  for (int r = threadIdx.y; r < 32; r += 8)
    t[r][threadIdx.x] = src[(size_t)(s0 + r) * 3072 + d0 + threadIdx.x];
  __syncthreads();
  u16* dst = vT + ((size_t)bh * 64 + d0) * 2048 + s0;
  for (int r = threadIdx.y; r < 32; r += 8)
    dst[(size_t)r * 2048 + threadIdx.x] = t[threadIdx.x][r];
}

// ---------------- bf16 GEMM: C[M][N] = A[M][K] @ Bt[N][K]^T ----------------
// 128x128 tile, BK=32, 4 waves (2x2), mfma 16x16x32, 4x4 frags per wave.
template<int BIAS, int RELU, int RES, int OUTBF>
__global__ __launch_bounds__(256, 2)
void gemm_bt(const u16* __restrict__ A, const u16* __restrict__ Bt,
             const float* __restrict__ bias, const float* __restrict__ res,
             void* __restrict__ C, int M, int N, int K) {
  __shared__ u16 As[128 * 32];
  __shared__ u16 Bs[128 * 32];
  const int tid = threadIdx.x;
  const int wv = tid >> 6, lane = tid & 63;
  const int bm = blockIdx.y * 128, bn = blockIdx.x * 128;
  const int wr = wv >> 1, wc = wv & 1;
  const int l16 = lane & 15, lk = (lane >> 4) * 8;
  const int srow = lane >> 2, sc = (lane & 3) * 8;

  f32x4 acc[4][4] = {};

  const u16* Ag = A + (size_t)(bm + wv * 32 + srow) * K + sc;
  const u16* Bg = Bt + (size_t)(bn + wv * 32 + srow) * K + sc;
  u16* Al = As + (wv * 32) * 32;
  u16* Bl = Bs + (wv * 32) * 32;

  for (int k0 = 0; k0 < K; k0 += 32) {
    __syncthreads();
    gload16(Ag + k0, Al);
    gload16(Ag + (size_t)16 * K + k0, Al + 16 * 32);
    gload16(Bg + k0, Bl);
    gload16(Bg + (size_t)16 * K + k0, Bl + 16 * 32);
    __syncthreads();
    bf16x8 af[4], bfv[4];
#pragma unroll
    for (int i = 0; i < 4; i++)
      af[i] = *(const bf16x8*)&As[(wr * 64 + i * 16 + l16) * 32 + lk];
#pragma unroll
    for (int j = 0; j < 4; j++)
      bfv[j] = *(const bf16x8*)&Bs[(wc * 64 + j * 16 + l16) * 32 + lk];
#pragma unroll
    for (int i = 0; i < 4; i++)
#pragma unroll
      for (int j = 0; j < 4; j++)
        acc[i][j] = __builtin_amdgcn_mfma_f32_16x16x32_bf16(af[i], bfv[j], acc[i][j], 0, 0, 0);
  }

#pragma unroll
  for (int i = 0; i < 4; i++) {
#pragma unroll
    for (int j = 0; j < 4; j++) {
      const int col = bn + wc * 64 + j * 16 + l16;
      const float bv = BIAS ? bias[col] : 0.0f;
#pragma unroll
      for (int r = 0; r < 4; r++) {
        const int row = bm + wr * 64 + i * 16 + (lane >> 4) * 4 + r;
        float v = acc[i][j][r] + bv;
        if (RELU) v = fmaxf(v, 0.0f);
        if (RES) v += res[(size_t)row * N + col];
        if (OUTBF) ((u16*)C)[(size_t)row * N + col] = f2bf(v);
        else       ((float*)C)[(size_t)row * N + col] = v;
      }
    }
  }
}

// ---------------- Flash attention: 4 waves/block, 16 q-rows/wave ----------------
// qkv bf16 [m][3072] (q|k|v, head-major within each), vT bf16 [bh][64][2048].
__global__ __launch_bounds__(256, 2)
void attn_kernel(const u16* __restrict__ qkv, const u16* __restrict__ vT,
                 const int* __restrict__ mask, u16* __restrict__ aout) {
  __shared__ u16 Ks[64][72];      // [kv][dh] +8 pad
  __shared__ u16 Vs[64][72];      // [dh][kv] +8 pad
  __shared__ u16 Ps[4][16][72];   // per-wave P [q][kv] +8 pad
  const int tid = threadIdx.x;
  const int wv = tid >> 6, lane = tid & 63;
  const int bh = blockIdx.y, b = bh >> 4, h = bh & 15;
  const int q0 = blockIdx.x * 64 + wv * 16;
  const int l16 = lane & 15, lh = lane >> 4;

  // Q fragments, held for the whole kernel
  bf16x8 qf[2];
  {
    const u16* qp = qkv + ((size_t)(b * 2048) + q0 + l16) * 3072 + h * 64 + lh * 8;
    qf[0] = *(const bf16x8*)qp;
    qf[1] = *(const bf16x8*)(qp + 32);
  }

  float m_run[4] = {-INFINITY, -INFINITY, -INFINITY, -INFINITY};
  float l_run[4] = {0.f, 0.f, 0.f, 0.f};
  f32x4 oa[4] = {};

  const int strow = tid >> 3;          // 0..31
  const int stc = (tid & 7) * 8;       // 0..56
  const u16* Kg = qkv + ((size_t)(b * 2048) + strow) * 3072 + 1024 + h * 64 + stc;
  const u16* Vg = vT + ((size_t)bh * 64 + strow) * 2048 + stc;

  for (int kv0 = 0; kv0 < 2048; kv0 += 64) {
    // (A) global loads for this tile
    const uint4 kd0 = *(const uint4*)(Kg + (size_t)kv0 * 3072);
    const uint4 kd1 = *(const uint4*)(Kg + (size_t)(kv0 + 32) * 3072);
    const uint4 vd0 = *(const uint4*)(Vg + kv0);
    const uint4 vd1 = *(const uint4*)(Vg + (size_t)32 * 2048 + kv0);
    __syncthreads();                   // (B) prior tile's LDS reads done
    *(uint4*)&Ks[strow][stc] = kd0;    // (C) stage
    *(uint4*)&Ks[strow + 32][stc] = kd1;
    *(uint4*)&Vs[strow][stc] = vd0;
    *(uint4*)&Vs[strow + 32][stc] = vd1;
    __syncthreads();                   // (D)

    // (E) QK^T -> scores (16 q x 64 kv per wave)
    f32x4 s[4] = {};
#pragma unroll
    for (int n = 0; n < 4; n++) {
      const bf16x8 kf0 = *(const bf16x8*)&Ks[n * 16 + l16][lh * 8];
      const bf16x8 kf1 = *(const bf16x8*)&Ks[n * 16 + l16][32 + lh * 8];
      s[n] = __builtin_amdgcn_mfma_f32_16x16x32_bf16(qf[0], kf0, s[n], 0, 0, 0);
      s[n] = __builtin_amdgcn_mfma_f32_16x16x32_bf16(qf[1], kf1, s[n], 0, 0, 0);
    }
    // scale + mask + per-row max
    float mt[4] = {-1e30f, -1e30f, -1e30f, -1e30f};
#pragma unroll
    for (int n = 0; n < 4; n++) {
      const float mb = mask[b * 2048 + kv0 + n * 16 + l16] ? 0.0f : -1e9f;
#pragma unroll
      for (int j = 0; j < 4; j++) {
        const float sv = s[n][j] * 0.125f + mb;
        s[n][j] = sv;
        mt[j] = fmaxf(mt[j], sv);
      }
    }
#pragma unroll
    for (int off = 1; off < 16; off <<= 1)
#pragma unroll
      for (int j = 0; j < 4; j++)
        mt[j] = fmaxf(mt[j], __shfl_xor(mt[j], off, 64));
    float alpha[4], rs[4];
#pragma unroll
    for (int j = 0; j < 4; j++) {
      const float mn = fmaxf(m_run[j], mt[j]);
      alpha[j] = __expf(m_run[j] - mn);
      m_run[j] = mn;
      rs[j] = 0.f;
    }
#pragma unroll
    for (int n = 0; n < 4; n++)
#pragma unroll
      for (int j = 0; j < 4; j++) {
        const float p = __expf(s[n][j] - m_run[j]);
        s[n][j] = p;
        rs[j] += p;
      }
#pragma unroll
    for (int off = 1; off < 16; off <<= 1)
#pragma unroll
      for (int j = 0; j < 4; j++)
        rs[j] += __shfl_xor(rs[j], off, 64);
#pragma unroll
    for (int j = 0; j < 4; j++)
      l_run[j] = l_run[j] * alpha[j] + rs[j];
    // write P (bf16) to per-wave LDS
#pragma unroll
    for (int n = 0; n < 4; n++)
#pragma unroll
      for (int j = 0; j < 4; j++)
        Ps[wv][lh * 4 + j][n * 16 + l16] = f2bf(s[n][j]);
    __syncthreads();                   // (F) P visible wave-wide

    // (G) rescale O, then PV
#pragma unroll
    for (int d = 0; d < 4; d++)
#pragma unroll
      for (int j = 0; j < 4; j++)
        oa[d][j] *= alpha[j];
    const bf16x8 pf0 = *(const bf16x8*)&Ps[wv][l16][lh * 8];
    const bf16x8 pf1 = *(const bf16x8*)&Ps[wv][l16][32 + lh * 8];
#pragma unroll
    for (int d = 0; d < 4; d++) {
      const bf16x8 vf0 = *(const bf16x8*)&Vs[d * 16 + l16][lh * 8];
      const bf16x8 vf1 = *(const bf16x8*)&Vs[d * 16 + l16][32 + lh * 8];
      oa[d] = __builtin_amdgcn_mfma_f32_16x16x32_bf16(pf0, vf0, oa[d], 0, 0, 0);
      oa[d] = __builtin_amdgcn_mfma_f32_16x16x32_bf16(pf1, vf1, oa[d], 0, 0, 0);
    }
  }

  // epilogue: divide by softmax denom, write bf16 [m][1024]
#pragma unroll
  for (int j = 0; j < 4; j++) l_run[j] = 1.0f / l_run[j];
#pragma unroll
  for (int d = 0; d < 4; d++)
#pragma unroll
    for (int j = 0; j < 4; j++) {
      const size_t idx = ((size_t)(b * 2048) + q0 + lh * 4 + j) * 1024 + h * 64 + d * 16 + l16;
      aout[idx] = f2bf(oa[d][j] * l_run[j]);
    }
}

extern "C" void kernel_launch(void* const* d_in, const int* in_sizes, int n_in,
                              void* d_out, int out_size, void* d_ws, size_t ws_size,
                              hipStream_t stream) {
  (void)in_sizes; (void)n_in; (void)out_size; (void)ws_size;
  const float* x     = (const float*)d_in[0];
  const int*   mask  = (const int*)d_in[1];
  const float* w_qkv = (const float*)d_in[2];
  const float* w_out = (const float*)d_in[3];
  const float* b_out = (const float*)d_in[4];
  const float* g1    = (const float*)d_in[5];
  const float* be1   = (const float*)d_in[6];
  const float* g2    = (const float*)d_in[7];
  const float* be2   = (const float*)d_in[8];
  const float* w1    = (const float*)d_in[9];
  const float* b1    = (const float*)d_in[10];
  const float* w2    = (const float*)d_in[11];
  const float* b2    = (const float*)d_in[12];
  float* out = (float*)d_out;

  // workspace layout (bytes), total 83,886,080 (80 MB)
  char* ws = (char*)d_ws;
  u16* hA    = (u16*)(ws);             // 8 MB   LN1 out; reused for LN2 out
  u16* wqkvT = (u16*)(ws + 8388608);   // 6 MB
  u16* woutT = (u16*)(ws + 14680064);  // 2 MB
  u16* w1T   = (u16*)(ws + 16777216);  // 8 MB
  u16* w2T   = (u16*)(ws + 25165824);  // 8 MB
  u16* qkv   = (u16*)(ws + 33554432);  // 24 MB (dead after attention)
  u16* ffn1  = (u16*)(ws + 33554432);  // 32 MB, overlaps qkv (written later)
  u16* vTb   = (u16*)(ws + 67108864);  // 8 MB
  u16* aout  = (u16*)(ws + 75497472);  // 8 MB

  // 1. LN1: x -> hA (bf16)
  ln_kernel<<<4096, 256, 0, stream>>>(x, g1, be1, hA);
  // 2. weights -> bf16 transposed [N][K]
  transpose_cvt<<<dim3(96, 32),  dim3(32, 8), 0, stream>>>(w_qkv, wqkvT, 1024, 3072);
  transpose_cvt<<<dim3(32, 32),  dim3(32, 8), 0, stream>>>(w_out, woutT, 1024, 1024);
  transpose_cvt<<<dim3(128, 32), dim3(32, 8), 0, stream>>>(w1,    w1T,   1024, 4096);
  transpose_cvt<<<dim3(32, 128), dim3(32, 8), 0, stream>>>(w2,    w2T,   4096, 1024);
  // 3. qkv = hA @ w_qkv   [4096,3072] bf16
  gemm_bt<0, 0, 0, 1><<<dim3(24, 32), 256, 0, stream>>>(hA, wqkvT, nullptr, nullptr, qkv, 4096, 3072, 1024);
  // 4. V transpose per (b,h)
  vtrans<<<dim3(64, 32, 2), dim3(32, 8), 0, stream>>>(qkv, vTb);
  // 5. attention -> aout bf16 [4096,1024]
  attn_kernel<<<dim3(32, 32), 256, 0, stream>>>(qkv, vTb, mask, aout);
  // 6. x1 = x + aout @ w_out + b_out  -> d_out (fp32)
  gemm_bt<1, 0, 1, 0><<<dim3(8, 32), 256, 0, stream>>>(aout, woutT, b_out, x, out, 4096, 1024, 1024);
  // 7. LN2: d_out -> hA (bf16)
  ln_kernel<<<4096, 256, 0, stream>>>(out, g2, be2, hA);
  // 8. ffn1 = relu(hA @ w1 + b1) -> bf16 [4096,4096]
  gemm_bt<1, 1, 0, 1><<<dim3(32, 32), 256, 0, stream>>>(hA, w1T, b1, nullptr, ffn1, 4096, 4096, 1024);
  // 9. out = d_out + ffn1 @ w2 + b2 -> d_out (fp32); per-element read-before-write, same thread
  gemm_bt<1, 0, 1, 0><<<dim3(8, 32), 256, 0, stream>>>(ffn1, w2T, b2, out, out, 4096, 1024, 4096);
}

// Round 2
// 308.921 us; speedup vs baseline: 1.1185x; 1.1185x over previous
//
#include <hip/hip_runtime.h>

typedef unsigned short u16;
typedef __bf16 bf16x8 __attribute__((ext_vector_type(8)));
typedef float f32x4 __attribute__((ext_vector_type(4)));

typedef __attribute__((address_space(1))) const void* as1cv;
typedef __attribute__((address_space(3))) void* as3v;

__device__ __forceinline__ u16 f2bf(float f) {
  union { float f; unsigned u; } v;
  v.f = f;
  unsigned r = (v.u + 0x7fffu + ((v.u >> 16) & 1u)) >> 16;
  return (u16)r;
}

__device__ __forceinline__ unsigned cvtpk(float lo, float hi) {
  unsigned r;
  asm("v_cvt_pk_bf16_f32 %0, %1, %2" : "=v"(r) : "v"(lo), "v"(hi));
  return r;
}

__device__ __forceinline__ void gload16(const void* g, void* l) {
  __builtin_amdgcn_global_load_lds((as1cv)g, (as3v)l, 16, 0, 0);
}

// ---------------- LayerNorm: fp32 [rows][1024] -> bf16 ----------------
__global__ __launch_bounds__(256)
void ln_kernel(const float* __restrict__ x, const float* __restrict__ g,
               const float* __restrict__ be, u16* __restrict__ out) {
  __shared__ float red[8];
  const int row = blockIdx.x;
  const int tid = threadIdx.x;
  const float4 v = ((const float4*)(x + (size_t)row * 1024))[tid];
  float s = v.x + v.y + v.z + v.w;
#pragma unroll
  for (int off = 1; off < 64; off <<= 1) s += __shfl_xor(s, off, 64);
  const int wv = tid >> 6, lane = tid & 63;
  if (lane == 0) red[wv] = s;
  __syncthreads();
  s = red[0] + red[1] + red[2] + red[3];
  const float mu = s * (1.0f / 1024.0f);
  const float d0 = v.x - mu, d1 = v.y - mu, d2 = v.z - mu, d3 = v.w - mu;
  float q = d0 * d0 + d1 * d1 + d2 * d2 + d3 * d3;
#pragma unroll
  for (int off = 1; off < 64; off <<= 1) q += __shfl_xor(q, off, 64);
  if (lane == 0) red[4 + wv] = q;
  __syncthreads();
  q = red[4] + red[5] + red[6] + red[7];
  const float inv = rsqrtf(q * (1.0f / 1024.0f) + 1e-5f);
  const float4 gv = ((const float4*)g)[tid];
  const float4 bv = ((const float4*)be)[tid];
  unsigned p0 = (unsigned)f2bf(d0 * inv * gv.x + bv.x) |
                ((unsigned)f2bf(d1 * inv * gv.y + bv.y) << 16);
  unsigned p1 = (unsigned)f2bf(d2 * inv * gv.z + bv.z) |
                ((unsigned)f2bf(d3 * inv * gv.w + bv.w) << 16);
  uint2 o; o.x = p0; o.y = p1;
  *(uint2*)(out + (size_t)row * 1024 + tid * 4) = o;
}

// ---------- weight convert+transpose: fp32 [K][N] -> bf16 [N][K] ----------
__global__ __launch_bounds__(256)
void transpose_cvt(const float* __restrict__ in, u16* __restrict__ out,
                   int K, int N) {
  __shared__ float t[32][33];
  const int n0 = blockIdx.x * 32, k0 = blockIdx.y * 32;
  for (int r = threadIdx.y; r < 32; r += 8)
    t[r][threadIdx.x] = in[(size_t)(k0 + r) * N + n0 + threadIdx.x];
  __syncthreads();
  for (int r = threadIdx.y; r < 32; r += 8)
    out[(size_t)(n0 + r) * K + k0 + threadIdx.x] = f2bf(t[threadIdx.x][r]);
}

// ---------- V transpose: qkv bf16 [m][3072] (V slice) -> vT [bh][64][2048] ----------
__global__ __launch_bounds__(256)
void vtrans(const u16* __restrict__ qkv, u16* __restrict__ vT) {
  __shared__ u16 t[32][33];
  const int s0 = blockIdx.x * 32;
  const int bh = blockIdx.y;
  const int d0 = blockIdx.z * 32;
  const int b = bh >> 4, h = bh & 15;
  const u16* src = qkv + ((size_t)b * 2048) * 3072 + 2048 + h * 64;
  for (int r = threadIdx.y; r < 32; r += 8)
    t[r][threadIdx.x] = src[(size_t)(s0 + r) * 3072 + d0 + threadIdx.x];
  __syncthreads();
  u16* dst = vT + ((size_t)bh * 64 + d0) * 2048 + s0;
  for (int r = threadIdx.y; r < 32; r += 8)
    dst[(size_t)r * 2048 + threadIdx.x] = t[threadIdx.x][r];
}

// ---------- mask -> additive bias in exp2 domain ----------
__global__ __launch_bounds__(256)
void maskbias(const int* __restrict__ mask, float* __restrict__ mb, int n) {
  int i = blockIdx.x * 256 + threadIdx.x;
  if (i < n) mb[i] = mask[i] ? 0.0f : -1.4426950408889634e9f;
}

// ---------------- bf16 GEMM: C[M][N] = A[M][K] @ Bt[N][K]^T ----------------
template<int BIAS, int RELU, int RES, int OUTBF>
__global__ __launch_bounds__(256, 2)
void gemm_bt(const u16* __restrict__ A, const u16* __restrict__ Bt,
             const float* __restrict__ bias, const float* __restrict__ res,
             void* __restrict__ C, int M, int N, int K) {
  __shared__ u16 As[128 * 32];
  __shared__ u16 Bs[128 * 32];
  const int tid = threadIdx.x;
  const int wv = tid >> 6, lane = tid & 63;
  const int bm = blockIdx.y * 128, bn = blockIdx.x * 128;
  const int wr = wv >> 1, wc = wv & 1;
  const int l16 = lane & 15, lk = (lane >> 4) * 8;
  const int srow = lane >> 2, sc = (lane & 3) * 8;

  f32x4 acc[4][4] = {};

  const u16* Ag = A + (size_t)(bm + wv * 32 + srow) * K + sc;
  const u16* Bg = Bt + (size_t)(bn + wv * 32 + srow) * K + sc;
  u16* Al = As + (wv * 32) * 32;
  u16* Bl = Bs + (wv * 32) * 32;

  for (int k0 = 0; k0 < K; k0 += 32) {
    __syncthreads();
    gload16(Ag + k0, Al);
    gload16(Ag + (size_t)16 * K + k0, Al + 16 * 32);
    gload16(Bg + k0, Bl);
    gload16(Bg + (size_t)16 * K + k0, Bl + 16 * 32);
    __syncthreads();
    bf16x8 af[4], bfv[4];
#pragma unroll
    for (int i = 0; i < 4; i++)
      af[i] = *(const bf16x8*)&As[(wr * 64 + i * 16 + l16) * 32 + lk];
#pragma unroll
    for (int j = 0; j < 4; j++)
      bfv[j] = *(const bf16x8*)&Bs[(wc * 64 + j * 16 + l16) * 32 + lk];
#pragma unroll
    for (int i = 0; i < 4; i++)
#pragma unroll
      for (int j = 0; j < 4; j++)
        acc[i][j] = __builtin_amdgcn_mfma_f32_16x16x32_bf16(af[i], bfv[j], acc[i][j], 0, 0, 0);
  }

#pragma unroll
  for (int i = 0; i < 4; i++) {
#pragma unroll
    for (int j = 0; j < 4; j++) {
      const int col = bn + wc * 64 + j * 16 + l16;
      const float bv = BIAS ? bias[col] : 0.0f;
#pragma unroll
      for (int r = 0; r < 4; r++) {
        const int row = bm + wr * 64 + i * 16 + (lane >> 4) * 4 + r;
        float v = acc[i][j][r] + bv;
        if (RELU) v = fmaxf(v, 0.0f);
        if (RES) v += res[(size_t)row * N + col];
        if (OUTBF) ((u16*)C)[(size_t)row * N + col] = f2bf(v);
        else       ((float*)C)[(size_t)row * N + col] = v;
      }
    }
  }
}

// ---------------- Flash attention v2: swapped operands, zero-LDS P ----------------
// 4 waves x 32 q-rows = 128 q per block. kv-tile 64, double-buffered LDS via
// global_load_lds with XOR-swizzled source. P stays in registers (k-slot
// permutation compensated in V reads). Softmax in exp2 domain, defer-max THR=8.
__global__ __launch_bounds__(256)
void attn2(const u16* __restrict__ qkv, const u16* __restrict__ vT,
           const float* __restrict__ mbg, u16* __restrict__ aout) {
  __shared__ u16 KsS[2][4096];   // [buf][64 kv][64 d], 16B-granule XOR swizzle by row&7
  __shared__ u16 VsS[2][4096];   // [buf][64 d][64 kv], same swizzle

  const int tid = threadIdx.x;
  const int wv = tid >> 6, lane = tid & 63;
  const int l16 = lane & 15, lh = lane >> 4;
  const int bh = blockIdx.y, b = bh >> 4, h = bh & 15;
  const int q0w = blockIdx.x * 128 + wv * 32;

  // Q fragments: qf[qb][c] = Q[q0w+qb*16+l16][c*32 + 8*lh .. +7]
  bf16x8 qf[2][2];
#pragma unroll
  for (int qb = 0; qb < 2; ++qb)
#pragma unroll
    for (int c = 0; c < 2; ++c)
      qf[qb][c] = *(const bf16x8*)(qkv + (size_t)(b * 2048 + q0w + qb * 16 + l16) * 3072 + h * 64 + c * 32 + 8 * lh);

  // LDS read offsets (u16 units), swizzle: byte_in_row ^= (row&7)<<4, row&7 == l16&7
  const int rs = (l16 & 7) << 4;
  const int koff0 = ((0 + 16 * lh) ^ rs) >> 1;         // c=0: byte 16*lh
  const int koff1 = ((64 + 16 * lh) ^ rs) >> 1;        // c=1: byte 64+16*lh
  int voff[2][2];
#pragma unroll
  for (int u = 0; u < 2; ++u)
#pragma unroll
    for (int w = 0; w < 2; ++w)
      voff[u][w] = ((64 * u + 32 * w + 8 * lh) ^ rs) >> 1;

  // staging source pointers (pre-swizzled global addresses)
  const int rl0 = wv * 8 + (lane >> 3);            // rows 0..31
  const int rl1 = 32 + wv * 8 + (lane >> 3);       // rows 32..63
  const int glog = (lane & 7) ^ ((lane >> 3) & 7); // logical 16B granule
  const u16* kg0 = qkv + (size_t)(b * 2048 + rl0) * 3072 + 1024 + h * 64 + 8 * glog;
  const u16* kg1 = qkv + (size_t)(b * 2048 + rl1) * 3072 + 1024 + h * 64 + 8 * glog;
  const u16* vg0 = vT + ((size_t)bh * 64 + rl0) * 2048 + 8 * glog;
  const u16* vg1 = vT + ((size_t)bh * 64 + rl1) * 2048 + 8 * glog;
  const float* mbp = mbg + b * 2048 + 4 * lh;

  // prologue: stage tile 0 into buf 0
  gload16(kg0, &KsS[0][wv * 512]);
  gload16(kg1, &KsS[0][2048 + wv * 512]);
  gload16(vg0, &VsS[0][wv * 512]);
  gload16(vg1, &VsS[0][2048 + wv * 512]);
  kg0 += 64 * 3072; kg1 += 64 * 3072; vg0 += 64; vg1 += 64;

  f32x4 mbc[4], mbn[4];
#pragma unroll
  for (int n = 0; n < 4; ++n) mbc[n] = *(const f32x4*)(mbp + n * 16);

  const float CL2 = 0.125f * 1.4426950408889634f;
  float m[2] = {-INFINITY, -INFINITY};
  float l[2] = {0.f, 0.f};
  f32x4 oT[4][2] = {};  // [D][qb]: O^T[d = D*16+4*lh+j][q = qb*16+l16]

  for (int t = 0; t < 32; ++t) {
    asm volatile("s_waitcnt vmcnt(0)" ::: "memory");
    __syncthreads();
    const int cur = t & 1;
    if (t + 1 < 32) {
      const int nx = cur ^ 1;
      gload16(kg0, &KsS[nx][wv * 512]);
      gload16(kg1, &KsS[nx][2048 + wv * 512]);
      gload16(vg0, &VsS[nx][wv * 512]);
      gload16(vg1, &VsS[nx][2048 + wv * 512]);
      kg0 += 64 * 3072; kg1 += 64 * 3072; vg0 += 64; vg1 += 64;
#pragma unroll
      for (int n = 0; n < 4; ++n) mbn[n] = *(const f32x4*)(mbp + (t + 1) * 64 + n * 16);
    }

    const u16* Kb = &KsS[cur][0];
    const u16* Vb = &VsS[cur][0];

    // ---- QK^T (swapped): s[qb][n] holds P[q=qb*16+l16][kv = n*16+4*lh+j] ----
    f32x4 s[2][4] = {};
#pragma unroll
    for (int c = 0; c < 2; ++c) {
      const int ko = c ? koff1 : koff0;
      bf16x8 kf[4];
#pragma unroll
      for (int n = 0; n < 4; ++n)
        kf[n] = *(const bf16x8*)(Kb + (n * 16 + l16) * 64 + ko);
#pragma unroll
      for (int qb = 0; qb < 2; ++qb)
#pragma unroll
        for (int n = 0; n < 4; ++n)
          s[qb][n] = __builtin_amdgcn_mfma_f32_16x16x32_bf16(kf[n], qf[qb][c], s[qb][n], 0, 0, 0);
    }

    // ---- scale + mask bias (exp2 domain), per-row max ----
    float pm[2] = {-3.0e38f, -3.0e38f};
#pragma unroll
    for (int qb = 0; qb < 2; ++qb) {
#pragma unroll
      for (int n = 0; n < 4; ++n)
#pragma unroll
        for (int j = 0; j < 4; ++j) {
          float v = fmaf(s[qb][n][j], CL2, mbc[n][j]);
          s[qb][n][j] = v;
          pm[qb] = fmaxf(pm[qb], v);
        }
      pm[qb] = fmaxf(pm[qb], __shfl_xor(pm[qb], 16, 64));
      pm[qb] = fmaxf(pm[qb], __shfl_xor(pm[qb], 32, 64));
    }

    // ---- defer-max rescale (THR=8 in log2 units) ----
    const bool need = (pm[0] > m[0] + 8.f) || (pm[1] > m[1] + 8.f);
    if (__any(need)) {
#pragma unroll
      for (int qb = 0; qb < 2; ++qb) {
        const float mn = fmaxf(m[qb], pm[qb]);
        const float a = __builtin_exp2f(m[qb] - mn);
        m[qb] = mn;
        l[qb] *= a;
#pragma unroll
        for (int D = 0; D < 4; ++D)
#pragma unroll
          for (int j = 0; j < 4; ++j)
            oT[D][qb][j] *= a;
      }
    }

    // ---- exp2 + row sum ----
#pragma unroll
    for (int qb = 0; qb < 2; ++qb) {
      float r = 0.f;
#pragma unroll
      for (int n = 0; n < 4; ++n)
#pragma unroll
        for (int j = 0; j < 4; ++j) {
          const float p = __builtin_exp2f(s[qb][n][j] - m[qb]);
          s[qb][n][j] = p;
          r += p;
        }
      r += __shfl_xor(r, 16, 64);
      r += __shfl_xor(r, 32, 64);
      l[qb] += r;
    }

    // ---- pack P to bf16 (in-register, k-slot permuted) ----
    union U8 { unsigned u[4]; bf16x8 v; };
    U8 pa[2][2];
#pragma unroll
    for (int qb = 0; qb < 2; ++qb)
#pragma unroll
      for (int u = 0; u < 2; ++u) {
        pa[qb][u].u[0] = cvtpk(s[qb][2 * u][0], s[qb][2 * u][1]);
        pa[qb][u].u[1] = cvtpk(s[qb][2 * u][2], s[qb][2 * u][3]);
        pa[qb][u].u[2] = cvtpk(s[qb][2 * u + 1][0], s[qb][2 * u + 1][1]);
        pa[qb][u].u[3] = cvtpk(s[qb][2 * u + 1][2], s[qb][2 * u + 1][3]);
      }

    // ---- PV (swapped): oT[D][qb] += V^T-frag * P-frag ----
#pragma unroll
    for (int u = 0; u < 2; ++u)
#pragma unroll
      for (int D = 0; D < 4; ++D) {
        const u16* vrow = Vb + (D * 16 + l16) * 64;
        U8 va;
        const uint2 w0 = *(const uint2*)(vrow + voff[u][0]);
        const uint2 w1 = *(const uint2*)(vrow + voff[u][1]);
        va.u[0] = w0.x; va.u[1] = w0.y; va.u[2] = w1.x; va.u[3] = w1.y;
#pragma unroll
        for (int qb = 0; qb < 2; ++qb)
          oT[D][qb] = __builtin_amdgcn_mfma_f32_16x16x32_bf16(va.v, pa[qb][u].v, oT[D][qb], 0, 0, 0);
      }

#pragma unroll
    for (int n = 0; n < 4; ++n) mbc[n] = mbn[n];
  }

  // ---- epilogue: normalize, write O (bf16 [m][1024]) ----
  const float r0 = 1.0f / l[0], r1 = 1.0f / l[1];
#pragma unroll
  for (int D = 0; D < 4; ++D)
#pragma unroll
    for (int qb = 0; qb < 2; ++qb) {
      const float rr = qb ? r1 : r0;
      uint2 o;
      o.x = cvtpk(oT[D][qb][0] * rr, oT[D][qb][1] * rr);
      o.y = cvtpk(oT[D][qb][2] * rr, oT[D][qb][3] * rr);
      *(uint2*)(aout + (size_t)(b * 2048 + q0w + qb * 16 + l16) * 1024 + h * 64 + D * 16 + 4 * lh) = o;
    }
}

extern "C" void kernel_launch(void* const* d_in, const int* in_sizes, int n_in,
                              void* d_out, int out_size, void* d_ws, size_t ws_size,
                              hipStream_t stream) {
  (void)in_sizes; (void)n_in; (void)out_size; (void)ws_size;
  const float* x     = (const float*)d_in[0];
  const int*   mask  = (const int*)d_in[1];
  const float* w_qkv = (const float*)d_in[2];
  const float* w_out = (const float*)d_in[3];
  const float* b_out = (const float*)d_in[4];
  const float* g1    = (const float*)d_in[5];
  const float* be1   = (const float*)d_in[6];
  const float* g2    = (const float*)d_in[7];
  const float* be2   = (const float*)d_in[8];
  const float* w1    = (const float*)d_in[9];
  const float* b1    = (const float*)d_in[10];
  const float* w2    = (const float*)d_in[11];
  const float* b2    = (const float*)d_in[12];
  float* out = (float*)d_out;

  // workspace layout (bytes), total 83,886,080 (80 MB)
  char* ws = (char*)d_ws;
  u16* hA    = (u16*)(ws);             // 8 MB   LN1 out; reused for LN2 out
  u16* wqkvT = (u16*)(ws + 8388608);   // 6 MB
  u16* woutT = (u16*)(ws + 14680064);  // 2 MB
  u16* w1T   = (u16*)(ws + 16777216);  // 8 MB
  u16* w2T   = (u16*)(ws + 25165824);  // 8 MB
  u16* qkv   = (u16*)(ws + 33554432);  // 24 MB (dead after attention)
  u16* ffn1  = (u16*)(ws + 33554432);  // 32 MB, overlaps qkv (written later)
  u16* vTb   = (u16*)(ws + 67108864);  // 8 MB
  u16* aout  = (u16*)(ws + 75497472);  // 8 MB
  float* mb  = (float*)d_out;          // 16 KB scratch in d_out (dead until step 6)

  // 1. LN1: x -> hA (bf16)
  ln_kernel<<<4096, 256, 0, stream>>>(x, g1, be1, hA);
  // 1b. mask bias (exp2 domain)
  maskbias<<<16, 256, 0, stream>>>(mask, mb, 4096);
  // 2. weights -> bf16 transposed [N][K]
  transpose_cvt<<<dim3(96, 32),  dim3(32, 8), 0, stream>>>(w_qkv, wqkvT, 1024, 3072);
  transpose_cvt<<<dim3(32, 32),  dim3(32, 8), 0, stream>>>(w_out, woutT, 1024, 1024);
  transpose_cvt<<<dim3(128, 32), dim3(32, 8), 0, stream>>>(w1,    w1T,   1024, 4096);
  transpose_cvt<<<dim3(32, 128), dim3(32, 8), 0, stream>>>(w2,    w2T,   4096, 1024);
  // 3. qkv = hA @ w_qkv   [4096,3072] bf16
  gemm_bt<0, 0, 0, 1><<<dim3(24, 32), 256, 0, stream>>>(hA, wqkvT, nullptr, nullptr, qkv, 4096, 3072, 1024);
  // 4. V transpose per (b,h)
  vtrans<<<dim3(64, 32, 2), dim3(32, 8), 0, stream>>>(qkv, vTb);
  // 5. attention -> aout bf16 [4096,1024]
  attn2<<<dim3(16, 32), 256, 0, stream>>>(qkv, vTb, mb, aout);
  // 6. x1 = x + aout @ w_out + b_out  -> d_out (fp32)
  gemm_bt<1, 0, 1, 0><<<dim3(8, 32), 256, 0, stream>>>(aout, woutT, b_out, x, out, 4096, 1024, 1024);
  // 7. LN2: d_out -> hA (bf16)
  ln_kernel<<<4096, 256, 0, stream>>>(out, g2, be2, hA);
  // 8. ffn1 = relu(hA @ w1 + b1) -> bf16 [4096,4096]
  gemm_bt<1, 1, 0, 1><<<dim3(32, 32), 256, 0, stream>>>(hA, w1T, b1, nullptr, ffn1, 4096, 4096, 1024);
  // 9. out = d_out + ffn1 @ w2 + b2 -> d_out (fp32); per-element read-before-write, same thread
  gemm_bt<1, 0, 1, 0><<<dim3(8, 32), 256, 0, stream>>>(ffn1, w2T, b2, out, out, 4096, 1024, 4096);
}

// Round 3
// 302.966 us; speedup vs baseline: 1.1405x; 1.0197x over previous
//
#include <hip/hip_runtime.h>

typedef unsigned short u16;
typedef __bf16 bf16x8 __attribute__((ext_vector_type(8)));
typedef float f32x4 __attribute__((ext_vector_type(4)));

typedef __attribute__((address_space(1))) const void* as1cv;
typedef __attribute__((address_space(3))) void* as3v;

__device__ __forceinline__ u16 f2bf(float f) {
  union { float f; unsigned u; } v;
  v.f = f;
  unsigned r = (v.u + 0x7fffu + ((v.u >> 16) & 1u)) >> 16;
  return (u16)r;
}

__device__ __forceinline__ unsigned cvtpk(float lo, float hi) {
  unsigned r;
  asm("v_cvt_pk_bf16_f32 %0, %1, %2" : "=v"(r) : "v"(lo), "v"(hi));
  return r;
}

__device__ __forceinline__ void gload16(const void* g, void* l) {
  __builtin_amdgcn_global_load_lds((as1cv)g, (as3v)l, 16, 0, 0);
}

// ---------------- LayerNorm: fp32 [rows][1024] -> bf16 ----------------
__global__ __launch_bounds__(256)
void ln_kernel(const float* __restrict__ x, const float* __restrict__ g,
               const float* __restrict__ be, u16* __restrict__ out) {
  __shared__ float red[8];
  const int row = blockIdx.x;
  const int tid = threadIdx.x;
  const float4 v = ((const float4*)(x + (size_t)row * 1024))[tid];
  float s = v.x + v.y + v.z + v.w;
#pragma unroll
  for (int off = 1; off < 64; off <<= 1) s += __shfl_xor(s, off, 64);
  const int wv = tid >> 6, lane = tid & 63;
  if (lane == 0) red[wv] = s;
  __syncthreads();
  s = red[0] + red[1] + red[2] + red[3];
  const float mu = s * (1.0f / 1024.0f);
  const float d0 = v.x - mu, d1 = v.y - mu, d2 = v.z - mu, d3 = v.w - mu;
  float q = d0 * d0 + d1 * d1 + d2 * d2 + d3 * d3;
#pragma unroll
  for (int off = 1; off < 64; off <<= 1) q += __shfl_xor(q, off, 64);
  if (lane == 0) red[4 + wv] = q;
  __syncthreads();
  q = red[4] + red[5] + red[6] + red[7];
  const float inv = rsqrtf(q * (1.0f / 1024.0f) + 1e-5f);
  const float4 gv = ((const float4*)g)[tid];
  const float4 bv = ((const float4*)be)[tid];
  unsigned p0 = (unsigned)f2bf(d0 * inv * gv.x + bv.x) |
                ((unsigned)f2bf(d1 * inv * gv.y + bv.y) << 16);
  unsigned p1 = (unsigned)f2bf(d2 * inv * gv.z + bv.z) |
                ((unsigned)f2bf(d3 * inv * gv.w + bv.w) << 16);
  uint2 o; o.x = p0; o.y = p1;
  *(uint2*)(out + (size_t)row * 1024 + tid * 4) = o;
}

// ---------- weight convert+transpose: fp32 [K][N] -> bf16 [N][K] ----------
__global__ __launch_bounds__(256)
void transpose_cvt(const float* __restrict__ in, u16* __restrict__ out,
                   int K, int N) {
  __shared__ float t[32][33];
  const int n0 = blockIdx.x * 32, k0 = blockIdx.y * 32;
  for (int r = threadIdx.y; r < 32; r += 8)
    t[r][threadIdx.x] = in[(size_t)(k0 + r) * N + n0 + threadIdx.x];
  __syncthreads();
  for (int r = threadIdx.y; r < 32; r += 8)
    out[(size_t)(n0 + r) * K + k0 + threadIdx.x] = f2bf(t[threadIdx.x][r]);
}

// ---------- V transpose+permute: qkv bf16 [m][3072] (V slice) -> vT ----------
// vT[bh][d][kv'] where within each 64-block of kv, position is permuted:
// kv = u*32 + w*16 + lh*4 + j  ->  p = u*32 + lh*8 + w*4 + j
// so the attn PV A-fragment (16B per lane) is contiguous in LDS.
__global__ __launch_bounds__(256)
void vtrans(const u16* __restrict__ qkv, u16* __restrict__ vT) {
  __shared__ u16 t[32][33];
  const int s0 = blockIdx.x * 32;
  const int bh = blockIdx.y;
  const int d0 = blockIdx.z * 32;
  const int b = bh >> 4, h = bh & 15;
  const u16* src = qkv + ((size_t)b * 2048) * 3072 + 2048 + h * 64;
  for (int r = threadIdx.y; r < 32; r += 8)
    t[r][threadIdx.x] = src[(size_t)(s0 + r) * 3072 + d0 + threadIdx.x];
  __syncthreads();
  const int kvl = (s0 & 32) + threadIdx.x;
  const int p = (kvl & 32) | (((kvl >> 2) & 3) << 3) | (((kvl >> 4) & 1) << 2) | (kvl & 3);
  u16* dstp = vT + ((size_t)bh * 64 + d0) * 2048 + (s0 & ~63) + p;
  for (int r = threadIdx.y; r < 32; r += 8)
    dstp[(size_t)r * 2048] = t[threadIdx.x][r];
}

// ---------- mask -> additive bias in exp2 domain ----------
__global__ __launch_bounds__(256)
void maskbias(const int* __restrict__ mask, float* __restrict__ mb, int n) {
  int i = blockIdx.x * 256 + threadIdx.x;
  if (i < n) mb[i] = mask[i] ? 0.0f : -1.4426950408889634e9f;
}

// ---------------- bf16 GEMM: C[M][N] = A[M][K] @ Bt[N][K]^T ----------------
template<int BIAS, int RELU, int RES, int OUTBF>
__global__ __launch_bounds__(256, 2)
void gemm_bt(const u16* __restrict__ A, const u16* __restrict__ Bt,
             const float* __restrict__ bias, const float* __restrict__ res,
             void* __restrict__ C, int M, int N, int K) {
  __shared__ u16 As[128 * 32];
  __shared__ u16 Bs[128 * 32];
  const int tid = threadIdx.x;
  const int wv = tid >> 6, lane = tid & 63;
  const int bm = blockIdx.y * 128, bn = blockIdx.x * 128;
  const int wr = wv >> 1, wc = wv & 1;
  const int l16 = lane & 15, lk = (lane >> 4) * 8;
  const int srow = lane >> 2, sc = (lane & 3) * 8;

  f32x4 acc[4][4] = {};

  const u16* Ag = A + (size_t)(bm + wv * 32 + srow) * K + sc;
  const u16* Bg = Bt + (size_t)(bn + wv * 32 + srow) * K + sc;
  u16* Al = As + (wv * 32) * 32;
  u16* Bl = Bs + (wv * 32) * 32;

  for (int k0 = 0; k0 < K; k0 += 32) {
    __syncthreads();
    gload16(Ag + k0, Al);
    gload16(Ag + (size_t)16 * K + k0, Al + 16 * 32);
    gload16(Bg + k0, Bl);
    gload16(Bg + (size_t)16 * K + k0, Bl + 16 * 32);
    __syncthreads();
    bf16x8 af[4], bfv[4];
#pragma unroll
    for (int i = 0; i < 4; i++)
      af[i] = *(const bf16x8*)&As[(wr * 64 + i * 16 + l16) * 32 + lk];
#pragma unroll
    for (int j = 0; j < 4; j++)
      bfv[j] = *(const bf16x8*)&Bs[(wc * 64 + j * 16 + l16) * 32 + lk];
#pragma unroll
    for (int i = 0; i < 4; i++)
#pragma unroll
      for (int j = 0; j < 4; j++)
        acc[i][j] = __builtin_amdgcn_mfma_f32_16x16x32_bf16(af[i], bfv[j], acc[i][j], 0, 0, 0);
  }

#pragma unroll
  for (int i = 0; i < 4; i++) {
#pragma unroll
    for (int j = 0; j < 4; j++) {
      const int col = bn + wc * 64 + j * 16 + l16;
      const float bv = BIAS ? bias[col] : 0.0f;
#pragma unroll
      for (int r = 0; r < 4; r++) {
        const int row = bm + wr * 64 + i * 16 + (lane >> 4) * 4 + r;
        float v = acc[i][j][r] + bv;
        if (RELU) v = fmaxf(v, 0.0f);
        if (RES) v += res[(size_t)row * N + col];
        if (OUTBF) ((u16*)C)[(size_t)row * N + col] = f2bf(v);
        else       ((float*)C)[(size_t)row * N + col] = v;
      }
    }
  }
}

// ---------------- Flash attention v3: 64 q/block, 16 q/wave ----------------
// grid (32 q-tiles, 32 bh); 4 blocks/CU. Swapped-operand QK^T and PV, P in
// registers, V pre-permuted so PV A-frags are single ds_read_b128. Mask bias
// staged in LDS. Softmax exp2-domain with defer-max THR=8.
__global__ __launch_bounds__(256, 4)
void attn3(const u16* __restrict__ qkv, const u16* __restrict__ vT,
           const float* __restrict__ mbg, u16* __restrict__ aout) {
  __shared__ u16 KsS[2][4096];   // [buf][64 kv][64 d], 16B-granule XOR swizzle by row&7
  __shared__ u16 VsS[2][4096];   // [buf][64 d][64 kv-perm], same swizzle
  __shared__ float mbL[2048];    // mask bias row for this b

  const int tid = threadIdx.x;
  const int wv = tid >> 6, lane = tid & 63;
  const int l16 = lane & 15, lh = lane >> 4;
  const int bh = blockIdx.y, b = bh >> 4, h = bh & 15;
  const int q0 = blockIdx.x * 64 + wv * 16;

  // stage mask-bias row (visible after first loop barrier)
  {
    const float4* srcm = (const float4*)(mbg + b * 2048);
    float4* dstm = (float4*)mbL;
    dstm[tid] = srcm[tid];
    dstm[tid + 256] = srcm[tid + 256];
  }

  // Q fragments: qf[c] = Q[q0+l16][c*32 + 8*lh .. +7]
  bf16x8 qf[2];
#pragma unroll
  for (int c = 0; c < 2; ++c)
    qf[c] = *(const bf16x8*)(qkv + (size_t)(b * 2048 + q0 + l16) * 3072 + h * 64 + c * 32 + 8 * lh);

  // LDS read offsets (u16 units), swizzle: byte_in_row ^= (row&7)<<4, row&7 == l16&7
  const int rs = (l16 & 7) << 4;
  const int koff0 = ((16 * lh) ^ rs) >> 1;
  const int koff1 = ((64 + 16 * lh) ^ rs) >> 1;
  const int voff0 = koff0, voff1 = koff1;   // same pattern for permuted V

  // staging source pointers (pre-swizzled global addresses)
  const int rl0 = wv * 8 + (lane >> 3);            // rows 0..31
  const int rl1 = 32 + wv * 8 + (lane >> 3);       // rows 32..63
  const int glog = (lane & 7) ^ ((lane >> 3) & 7); // logical 16B granule
  const u16* kg0 = qkv + (size_t)(b * 2048 + rl0) * 3072 + 1024 + h * 64 + 8 * glog;
  const u16* kg1 = qkv + (size_t)(b * 2048 + rl1) * 3072 + 1024 + h * 64 + 8 * glog;
  const u16* vg0 = vT + ((size_t)bh * 64 + rl0) * 2048 + 8 * glog;
  const u16* vg1 = vT + ((size_t)bh * 64 + rl1) * 2048 + 8 * glog;

  // prologue: stage tile 0 into buf 0
  gload16(kg0, &KsS[0][wv * 512]);
  gload16(kg1, &KsS[0][2048 + wv * 512]);
  gload16(vg0, &VsS[0][wv * 512]);
  gload16(vg1, &VsS[0][2048 + wv * 512]);
  kg0 += 64 * 3072; kg1 += 64 * 3072; vg0 += 64; vg1 += 64;

  const float CL2 = 0.125f * 1.4426950408889634f;
  float m = -INFINITY, l = 0.f;
  f32x4 oT[4] = {};  // [D]: O^T[d = D*16+4*lh+j][q = l16]

  for (int t = 0; t < 32; ++t) {
    asm volatile("s_waitcnt vmcnt(0)" ::: "memory");
    __syncthreads();
    const int cur = t & 1;
    if (t + 1 < 32) {
      const int nx = cur ^ 1;
      gload16(kg0, &KsS[nx][wv * 512]);
      gload16(kg1, &KsS[nx][2048 + wv * 512]);
      gload16(vg0, &VsS[nx][wv * 512]);
      gload16(vg1, &VsS[nx][2048 + wv * 512]);
      kg0 += 64 * 3072; kg1 += 64 * 3072; vg0 += 64; vg1 += 64;
    }

    const u16* Kb = &KsS[cur][0];
    const u16* Vb = &VsS[cur][0];

    // mask bias for this tile (LDS, broadcast-friendly)
    f32x4 mbc[4];
#pragma unroll
    for (int n = 0; n < 4; ++n)
      mbc[n] = *(const f32x4*)&mbL[t * 64 + n * 16 + 4 * lh];

    // ---- QK^T (swapped): s[n] holds P[q=l16][kv = n*16+4*lh+j] ----
    f32x4 s[4] = {};
    __builtin_amdgcn_s_setprio(1);
#pragma unroll
    for (int c = 0; c < 2; ++c) {
      const int ko = c ? koff1 : koff0;
      bf16x8 kf[4];
#pragma unroll
      for (int n = 0; n < 4; ++n)
        kf[n] = *(const bf16x8*)(Kb + (n * 16 + l16) * 64 + ko);
#pragma unroll
      for (int n = 0; n < 4; ++n)
        s[n] = __builtin_amdgcn_mfma_f32_16x16x32_bf16(kf[n], qf[c], s[n], 0, 0, 0);
    }
    __builtin_amdgcn_s_setprio(0);

    // ---- scale + mask bias (exp2 domain), per-row max ----
    float pm = -3.0e38f;
#pragma unroll
    for (int n = 0; n < 4; ++n)
#pragma unroll
      for (int j = 0; j < 4; ++j) {
        const float v = fmaf(s[n][j], CL2, mbc[n][j]);
        s[n][j] = v;
        pm = fmaxf(pm, v);
      }
    pm = fmaxf(pm, __shfl_xor(pm, 16, 64));
    pm = fmaxf(pm, __shfl_xor(pm, 32, 64));

    // ---- defer-max rescale (THR=8 in log2 units) ----
    if (__any(pm > m + 8.f)) {
      const float mn = fmaxf(m, pm);
      const float a = __builtin_exp2f(m - mn);
      m = mn;
      l *= a;
#pragma unroll
      for (int D = 0; D < 4; ++D)
#pragma unroll
        for (int j = 0; j < 4; ++j)
          oT[D][j] *= a;
    }

    // ---- exp2 + row sum ----
    float r = 0.f;
#pragma unroll
    for (int n = 0; n < 4; ++n)
#pragma unroll
      for (int j = 0; j < 4; ++j) {
        const float p = __builtin_exp2f(s[n][j] - m);
        s[n][j] = p;
        r += p;
      }
    r += __shfl_xor(r, 16, 64);
    r += __shfl_xor(r, 32, 64);
    l += r;

    // ---- pack P to bf16 (in-register, k-slot order [w][j] matches vT perm) ----
    union U8 { unsigned u[4]; bf16x8 v; };
    U8 pa[2];
#pragma unroll
    for (int u = 0; u < 2; ++u) {
      pa[u].u[0] = cvtpk(s[2 * u][0], s[2 * u][1]);
      pa[u].u[1] = cvtpk(s[2 * u][2], s[2 * u][3]);
      pa[u].u[2] = cvtpk(s[2 * u + 1][0], s[2 * u + 1][1]);
      pa[u].u[3] = cvtpk(s[2 * u + 1][2], s[2 * u + 1][3]);
    }

    // ---- PV (swapped): oT[D] += V-frag * P-frag ----
    __builtin_amdgcn_s_setprio(1);
#pragma unroll
    for (int u = 0; u < 2; ++u) {
      const int vo = u ? voff1 : voff0;
#pragma unroll
      for (int D = 0; D < 4; ++D) {
        const bf16x8 va = *(const bf16x8*)(Vb + (D * 16 + l16) * 64 + vo);
        oT[D] = __builtin_amdgcn_mfma_f32_16x16x32_bf16(va, pa[u].v, oT[D], 0, 0, 0);
      }
    }
    __builtin_amdgcn_s_setprio(0);
  }

  // ---- epilogue: normalize, write O (bf16 [m][1024]) ----
  const float rr = 1.0f / l;
#pragma unroll
  for (int D = 0; D < 4; ++D) {
    uint2 o;
    o.x = cvtpk(oT[D][0] * rr, oT[D][1] * rr);
    o.y = cvtpk(oT[D][2] * rr, oT[D][3] * rr);
    *(uint2*)(aout + (size_t)(b * 2048 + q0 + l16) * 1024 + h * 64 + D * 16 + 4 * lh) = o;
  }
}

extern "C" void kernel_launch(void* const* d_in, const int* in_sizes, int n_in,
                              void* d_out, int out_size, void* d_ws, size_t ws_size,
                              hipStream_t stream) {
  (void)in_sizes; (void)n_in; (void)out_size; (void)ws_size;
  const float* x     = (const float*)d_in[0];
  const int*   mask  = (const int*)d_in[1];
  const float* w_qkv = (const float*)d_in[2];
  const float* w_out = (const float*)d_in[3];
  const float* b_out = (const float*)d_in[4];
  const float* g1    = (const float*)d_in[5];
  const float* be1   = (const float*)d_in[6];
  const float* g2    = (const float*)d_in[7];
  const float* be2   = (const float*)d_in[8];
  const float* w1    = (const float*)d_in[9];
  const float* b1    = (const float*)d_in[10];
  const float* w2    = (const float*)d_in[11];
  const float* b2    = (const float*)d_in[12];
  float* out = (float*)d_out;

  // workspace layout (bytes), total 83,886,080 (80 MB)
  char* ws = (char*)d_ws;
  u16* hA    = (u16*)(ws);             // 8 MB   LN1 out; reused for LN2 out
  u16* wqkvT = (u16*)(ws + 8388608);   // 6 MB
  u16* woutT = (u16*)(ws + 14680064);  // 2 MB
  u16* w1T   = (u16*)(ws + 16777216);  // 8 MB
  u16* w2T   = (u16*)(ws + 25165824);  // 8 MB
  u16* qkv   = (u16*)(ws + 33554432);  // 24 MB (dead after attention)
  u16* ffn1  = (u16*)(ws + 33554432);  // 32 MB, overlaps qkv (written later)
  u16* vTb   = (u16*)(ws + 67108864);  // 8 MB
  u16* aout  = (u16*)(ws + 75497472);  // 8 MB
  float* mb  = (float*)d_out;          // 16 KB scratch in d_out (dead until step 6)

  // 1. LN1: x -> hA (bf16)
  ln_kernel<<<4096, 256, 0, stream>>>(x, g1, be1, hA);
  // 1b. mask bias (exp2 domain)
  maskbias<<<16, 256, 0, stream>>>(mask, mb, 4096);
  // 2. weights -> bf16 transposed [N][K]
  transpose_cvt<<<dim3(96, 32),  dim3(32, 8), 0, stream>>>(w_qkv, wqkvT, 1024, 3072);
  transpose_cvt<<<dim3(32, 32),  dim3(32, 8), 0, stream>>>(w_out, woutT, 1024, 1024);
  transpose_cvt<<<dim3(128, 32), dim3(32, 8), 0, stream>>>(w1,    w1T,   1024, 4096);
  transpose_cvt<<<dim3(32, 128), dim3(32, 8), 0, stream>>>(w2,    w2T,   4096, 1024);
  // 3. qkv = hA @ w_qkv   [4096,3072] bf16
  gemm_bt<0, 0, 0, 1><<<dim3(24, 32), 256, 0, stream>>>(hA, wqkvT, nullptr, nullptr, qkv, 4096, 3072, 1024);
  // 4. V transpose+permute per (b,h)
  vtrans<<<dim3(64, 32, 2), dim3(32, 8), 0, stream>>>(qkv, vTb);
  // 5. attention -> aout bf16 [4096,1024]
  attn3<<<dim3(32, 32), 256, 0, stream>>>(qkv, vTb, mb, aout);
  // 6. x1 = x + aout @ w_out + b_out  -> d_out (fp32)
  gemm_bt<1, 0, 1, 0><<<dim3(8, 32), 256, 0, stream>>>(aout, woutT, b_out, x, out, 4096, 1024, 1024);
  // 7. LN2: d_out -> hA (bf16)
  ln_kernel<<<4096, 256, 0, stream>>>(out, g2, be2, hA);
  // 8. ffn1 = relu(hA @ w1 + b1) -> bf16 [4096,4096]
  gemm_bt<1, 1, 0, 1><<<dim3(32, 32), 256, 0, stream>>>(hA, w1T, b1, nullptr, ffn1, 4096, 4096, 1024);
  // 9. out = d_out + ffn1 @ w2 + b2 -> d_out (fp32); per-element read-before-write, same thread
  gemm_bt<1, 0, 1, 0><<<dim3(8, 32), 256, 0, stream>>>(ffn1, w2T, b2, out, out, 4096, 1024, 4096);
}